// Round 2
// baseline (1635.237 us; speedup 1.0000x reference)
//
#include <hip/hip_runtime.h>
#include <cstdint>
#include <cstddef>

#define DIN 768
#define HD  256
#define LSEQ 512
#define IDIM 512

__device__ __forceinline__ float siluf(float v) { return v / (1.0f + __expf(-v)); }

// 8 cubic B-spline basis values, grid_size=5, order=3. Grid matches JAX exactly:
// grid[t] = (t-3)*0.4f - 1.0f, t=0..11 (arange(-3,9)*(2/5)-1 in f32).
__device__ __forceinline__ void bspline8(float x, float* bb) {
  float b[11];
#pragma unroll
  for (int t = 0; t < 11; ++t) {
    float g0 = (float)(t - 3) * 0.4f - 1.0f;
    float g1 = (float)(t - 2) * 0.4f - 1.0f;
    b[t] = (x >= g0 && x < g1) ? 1.0f : 0.0f;
  }
#pragma unroll
  for (int kk = 1; kk <= 3; ++kk) {
#pragma unroll
    for (int t = 0; t + kk < 11; ++t) {
      float gt   = (float)(t - 3) * 0.4f - 1.0f;
      float gtk  = (float)(t + kk - 3) * 0.4f - 1.0f;
      float gtk1 = (float)(t + kk - 2) * 0.4f - 1.0f;
      float gt1  = (float)(t - 2) * 0.4f - 1.0f;
      float left  = (x - gt) * (1.0f / (gtk - gt));
      float right = (gtk1 - x) * (1.0f / (gtk1 - gt1));
      b[t] = left * b[t] + right * b[t + 1];
    }
  }
#pragma unroll
  for (int j = 0; j < 8; ++j) bb[j] = b[j];
}

// ---- prep: transpose kan1 weights into coalesced [d][o] / [d][o][8] (ss folded in)
__global__ __launch_bounds__(256) void prep_w1_kernel(
    const float* __restrict__ bw, const float* __restrict__ sw, const float* __restrict__ ss,
    float* __restrict__ Wb, float* __restrict__ Ws)
{
  int idx = blockIdx.x * 256 + threadIdx.x;   // 768*256
  int d = idx >> 8;
  int o = idx & 255;
  Wb[idx] = bw[(size_t)o * DIN + d];
  float sc = ss[(size_t)o * DIN + d];
  const float* sp = &sw[((size_t)o * DIN + d) * 8];
  float4 s0 = *(const float4*)sp;
  float4 s1 = *(const float4*)(sp + 4);
  float4* wp = (float4*)&Ws[(size_t)idx * 8];
  wp[0] = make_float4(s0.x * sc, s0.y * sc, s0.z * sc, s0.w * sc);
  wp[1] = make_float4(s1.x * sc, s1.y * sc, s1.z * sc, s1.w * sc);
}

// ---- KAN-1 (spline + silu base) fused with LayerNorm epilogue
// 512 threads: o = tid&255, row-half = tid>>8. 32 rows/block, 256 blocks.
// 8 waves/block -> 2 waves/SIMD minimum (vs 1 at 256 thr) for latency hiding.
__global__ __launch_bounds__(512) void kan1_ln_kernel(
    const float* __restrict__ x, const float* __restrict__ Wb, const float* __restrict__ Ws,
    const float* __restrict__ lng, const float* __restrict__ lnb, float* __restrict__ h)
{
  const int ROWS = 32, DCH = 16, RH = 16;
  __shared__ float bas[DCH][ROWS][8];
  __shared__ float sil[DCH][ROWS];
  __shared__ float redS[8][RH];
  __shared__ float redQ[8][RH];
  __shared__ float mS[ROWS], mR[ROWS];
  int tid = threadIdx.x;
  int o = tid & 255;
  int rh = tid >> 8;            // 0/1 -> rows rh*16..rh*16+15
  int r0 = blockIdx.x * ROWS;
  float acc[RH];
#pragma unroll
  for (int r = 0; r < RH; ++r) acc[r] = 0.0f;

#pragma unroll 1
  for (int d0 = 0; d0 < DIN; d0 += DCH) {
    __syncthreads();
    {
      int p = tid;              // 512 == ROWS*DCH, exactly one per thread
      int r = p >> 4, dd = p & 15;
      float xv = x[(size_t)(r0 + r) * DIN + d0 + dd];
      float bb[8];
      bspline8(xv, bb);
      *(float4*)&bas[dd][r][0] = make_float4(bb[0], bb[1], bb[2], bb[3]);
      *(float4*)&bas[dd][r][4] = make_float4(bb[4], bb[5], bb[6], bb[7]);
      sil[dd][r] = siluf(xv);
    }
    __syncthreads();
#pragma unroll 1
    for (int dd = 0; dd < DCH; ++dd) {
      int d = d0 + dd;
      float wb = Wb[d * HD + o];
      const float4* wp = (const float4*)&Ws[((size_t)d * HD + o) * 8];
      float4 w0 = wp[0], w1 = wp[1];
#pragma unroll
      for (int r = 0; r < RH; ++r) {
        int rr = rh * RH + r;
        float4 b0 = *(const float4*)&bas[dd][rr][0];
        float4 b1 = *(const float4*)&bas[dd][rr][4];
        float s = sil[dd][rr];
        acc[r] += s * wb
                + b0.x * w0.x + b0.y * w0.y + b0.z * w0.z + b0.w * w0.w
                + b1.x * w1.x + b1.y * w1.y + b1.z * w1.z + b1.w * w1.w;
      }
    }
  }
  // LayerNorm over the 256 o-columns for each of 32 rows
  int lane = tid & 63, wid = tid >> 6;   // wid 0..7 (0..3: rows 0..15, 4..7: rows 16..31)
  __syncthreads();
#pragma unroll
  for (int r = 0; r < RH; ++r) {
    float v = acc[r];
    float s = v, q = v * v;
#pragma unroll
    for (int off = 1; off < 64; off <<= 1) { s += __shfl_xor(s, off); q += __shfl_xor(q, off); }
    if (lane == 0) { redS[wid][r] = s; redQ[wid][r] = q; }
  }
  __syncthreads();
  if (tid < ROWS) {
    int rr = tid;
    int hb = (rr >> 4) * 4;
    int r = rr & 15;
    float s = redS[hb][r] + redS[hb + 1][r] + redS[hb + 2][r] + redS[hb + 3][r];
    float q = redQ[hb][r] + redQ[hb + 1][r] + redQ[hb + 2][r] + redQ[hb + 3][r];
    float m = s * (1.0f / 256.0f);
    float var = q * (1.0f / 256.0f) - m * m;
    mS[rr] = m;
    mR[rr] = rsqrtf(var + 1e-5f);
  }
  __syncthreads();
  float g = lng[o], bv = lnb[o];
#pragma unroll
  for (int r = 0; r < RH; ++r) {
    int rr = rh * RH + r;
    h[(size_t)(r0 + rr) * HD + o] = (acc[r] - mS[rr]) * mR[rr] * g + bv;
  }
}

// ---- RMSNorm: one block per row of 256
__global__ __launch_bounds__(256) void rmsnorm_kernel(
    const float* __restrict__ in, const float* __restrict__ w, float* __restrict__ out)
{
  __shared__ float p[4];
  int row = blockIdx.x, tid = threadIdx.x;
  float v = in[(size_t)row * 256 + tid];
  float q = v * v;
#pragma unroll
  for (int off = 1; off < 64; off <<= 1) q += __shfl_xor(q, off);
  if ((tid & 63) == 0) p[tid >> 6] = q;
  __syncthreads();
  float s = p[0] + p[1] + p[2] + p[3];
  float rstd = rsqrtf(s * (1.0f / 256.0f) + 1e-5f);
  out[(size_t)row * 256 + tid] = w[tid] * v * rstd;
}

// ---- fp32 GEMM 128x(NH*64)x16, 256 threads, 8x(NH*4) per thread.
// C[M][N] = A[M][K]*W[N][K]^T (+C if EP). Requires M%128==0, N%(NH*64)==0, K%16==0.
// Fragment cols/rows split {t*4, 64+t*4} -> ds_read_b128 16B-stride across lanes
// = 2-way bank aliasing (free) instead of 4-way at 32B stride.
template<int NH, int EP>
__global__ __launch_bounds__(256) void gemm128(
    const float* __restrict__ A, const float* __restrict__ W, float* __restrict__ C,
    int N, int K)
{
  __shared__ float As[16][132];
  __shared__ float Wsm[16][NH * 64 + 4];
  int tid = threadIdx.x;
  int bx = blockIdx.x, by = blockIdx.y;
  int tx = tid & 15, ty = tid >> 4;
  int lr = tid >> 1;
  int lk = (tid & 1) << 3;
  int wr = (NH == 2) ? lr : (tid >> 2);
  int wk = (NH == 2) ? lk : ((tid & 3) << 2);
  const float* Ap = A + (size_t)(bx * 128 + lr) * K + lk;
  const float* Wp = W + (size_t)(by * (NH * 64) + wr) * K + wk;
  float acc[8][NH * 4];
#pragma unroll
  for (int i = 0; i < 8; ++i)
#pragma unroll
    for (int j = 0; j < NH * 4; ++j) acc[i][j] = 0.0f;

#pragma unroll 1
  for (int k0 = 0; k0 < K; k0 += 16) {
    float4 av0 = *(const float4*)(Ap + k0);
    float4 av1 = *(const float4*)(Ap + k0 + 4);
    float4 wv0 = *(const float4*)(Wp + k0);
    float4 wv1;
    if constexpr (NH == 2) wv1 = *(const float4*)(Wp + k0 + 4);
    __syncthreads();
    As[lk + 0][lr] = av0.x; As[lk + 1][lr] = av0.y; As[lk + 2][lr] = av0.z; As[lk + 3][lr] = av0.w;
    As[lk + 4][lr] = av1.x; As[lk + 5][lr] = av1.y; As[lk + 6][lr] = av1.z; As[lk + 7][lr] = av1.w;
    Wsm[wk + 0][wr] = wv0.x; Wsm[wk + 1][wr] = wv0.y; Wsm[wk + 2][wr] = wv0.z; Wsm[wk + 3][wr] = wv0.w;
    if constexpr (NH == 2) {
      Wsm[wk + 4][wr] = wv1.x; Wsm[wk + 5][wr] = wv1.y; Wsm[wk + 6][wr] = wv1.z; Wsm[wk + 7][wr] = wv1.w;
    }
    __syncthreads();
#pragma unroll
    for (int kk = 0; kk < 16; ++kk) {
      float4 a0 = *(const float4*)&As[kk][ty * 4];
      float4 a1 = *(const float4*)&As[kk][64 + ty * 4];
      float af[8] = {a0.x, a0.y, a0.z, a0.w, a1.x, a1.y, a1.z, a1.w};
      float wf[8];
      float4 b0 = *(const float4*)&Wsm[kk][tx * 4];
      wf[0] = b0.x; wf[1] = b0.y; wf[2] = b0.z; wf[3] = b0.w;
      if constexpr (NH == 2) {
        float4 b1 = *(const float4*)&Wsm[kk][64 + tx * 4];
        wf[4] = b1.x; wf[5] = b1.y; wf[6] = b1.z; wf[7] = b1.w;
      }
#pragma unroll
      for (int i = 0; i < 8; ++i)
#pragma unroll
        for (int j = 0; j < NH * 4; ++j)
          acc[i][j] += af[i] * wf[j];
    }
  }
#pragma unroll
  for (int i = 0; i < 8; ++i) {
    int rloc = (i < 4) ? (ty * 4 + i) : (60 + ty * 4 + i);  // 64 + ty*4 + (i-4)
    float* cp = C + (size_t)(bx * 128 + rloc) * N + by * (NH * 64) + tx * 4;
    float4 v0 = make_float4(acc[i][0], acc[i][1], acc[i][2], acc[i][3]);
    if constexpr (EP == 1) {
      float4 o = *(const float4*)cp;
      v0 = make_float4(o.x + v0.x, o.y + v0.y, o.z + v0.z, o.w + v0.w);
    }
    *(float4*)cp = v0;
    if constexpr (NH == 2) {
      float* cp1 = cp + 64;
      float4 v1 = make_float4(acc[i][4], acc[i][5], acc[i][6], acc[i][7]);
      if constexpr (EP == 1) {
        float4 o = *(const float4*)cp1;
        v1 = make_float4(o.x + v1.x, o.y + v1.y, o.z + v1.z, o.w + v1.w);
      }
      *(float4*)cp1 = v1;
    }
  }
}

// ---- fp32 GEMM 64x64x16, 4x4/thread — kept for N=48 (x_proj)
template<int EP>
__global__ __launch_bounds__(256) void gemm_nt(
    const float* __restrict__ A, const float* __restrict__ W, float* __restrict__ C,
    int M, int N, int K)
{
  __shared__ float As[16][68];
  __shared__ float Wsm[16][68];
  int tid = threadIdx.x;
  int bx = blockIdx.x, by = blockIdx.y;
  int tx = tid & 15, ty = tid >> 4;
  int lr = tid >> 2;
  int lk = (tid & 3) << 2;
  const float* Ap = A + (size_t)(bx * 64 + lr) * K + lk;
  int wrow = by * 64 + lr;
  bool wv = wrow < N;
  const float* Wp = W + (size_t)(wv ? wrow : 0) * K + lk;
  float acc[4][4];
#pragma unroll
  for (int i = 0; i < 4; ++i)
#pragma unroll
    for (int j = 0; j < 4; ++j) acc[i][j] = 0.0f;

#pragma unroll 1
  for (int k0 = 0; k0 < K; k0 += 16) {
    float4 av = *(const float4*)(Ap + k0);
    float4 wvv = wv ? *(const float4*)(Wp + k0) : make_float4(0.f, 0.f, 0.f, 0.f);
    __syncthreads();
    As[lk + 0][lr] = av.x; As[lk + 1][lr] = av.y; As[lk + 2][lr] = av.z; As[lk + 3][lr] = av.w;
    Wsm[lk + 0][lr] = wvv.x; Wsm[lk + 1][lr] = wvv.y; Wsm[lk + 2][lr] = wvv.z; Wsm[lk + 3][lr] = wvv.w;
    __syncthreads();
#pragma unroll
    for (int kk = 0; kk < 16; ++kk) {
      float4 a = *(const float4*)&As[kk][ty * 4];
      float4 b = *(const float4*)&Wsm[kk][tx * 4];
      acc[0][0] += a.x * b.x; acc[0][1] += a.x * b.y; acc[0][2] += a.x * b.z; acc[0][3] += a.x * b.w;
      acc[1][0] += a.y * b.x; acc[1][1] += a.y * b.y; acc[1][2] += a.y * b.z; acc[1][3] += a.y * b.w;
      acc[2][0] += a.z * b.x; acc[2][1] += a.z * b.y; acc[2][2] += a.z * b.z; acc[2][3] += a.z * b.w;
      acc[3][0] += a.w * b.x; acc[3][1] += a.w * b.y; acc[3][2] += a.w * b.z; acc[3][3] += a.w * b.w;
    }
  }
#pragma unroll
  for (int i = 0; i < 4; ++i) {
    int row = bx * 64 + ty * 4 + i;
    int col = by * 64 + tx * 4;
    float* cp = C + (size_t)row * N + col;
    if (col + 3 < N) {
      float4 o;
      if (EP == 1) {
        float4 old = *(const float4*)cp;
        o = make_float4(old.x + acc[i][0], old.y + acc[i][1], old.z + acc[i][2], old.w + acc[i][3]);
      } else {
        o = make_float4(acc[i][0], acc[i][1], acc[i][2], acc[i][3]);
      }
      *(float4*)cp = o;
    } else {
#pragma unroll
      for (int j = 0; j < 4; ++j) if (col + j < N) {
        float v = acc[i][j];
        if (EP == 1) v += cp[j];
        cp[j] = v;
      }
    }
  }
}

// ---- causal depthwise conv (K=4) + bias + SiLU, reading u-half of proj
__global__ __launch_bounds__(256) void conv_silu_kernel(
    const float* __restrict__ proj, const float* __restrict__ cw, const float* __restrict__ cb,
    float* __restrict__ u2)
{
  int idx = blockIdx.x * 256 + threadIdx.x;   // B*L*I = 4194304
  int i = idx & 511;
  int l = (idx >> 9) & 511;
  int bl = idx >> 9;
  const float* p = proj + (size_t)bl * 1024 + i;
  float4 w = *(const float4*)&cw[i * 4];
  float s = cb[i];
  s += (l >= 3) ? p[-3 * 1024] * w.x : 0.0f;
  s += (l >= 2) ? p[-2 * 1024] * w.y : 0.0f;
  s += (l >= 1) ? p[-1 * 1024] * w.z : 0.0f;
  s += p[0] * w.w;
  u2[idx] = siluf(s);
}

// ---- selective scan, dt-GEMM folded in. grid (I/64, B), 256 thr.
// 4 lanes per i (4 states each); y written in-place over u2 (same-wave lockstep).
__global__ __launch_bounds__(256) void scan_kernel(
    const float* __restrict__ ssm, float* __restrict__ u2, const float* __restrict__ proj,
    const float* __restrict__ dtw, const float* __restrict__ dtb, const float* __restrict__ alog,
    const float* __restrict__ Dp)
{
  const int CL = 64;
  __shared__ float sbuf[CL * 48];
  __shared__ float ubuf[CL][64];
  __shared__ float gbuf[CL][64];
  int tid = threadIdx.x;
  int il = tid >> 2, ns = tid & 3;
  int i0 = blockIdx.x * 64;
  int i = i0 + il;
  int b = blockIdx.y;
  float A4[4], wr4[4];
#pragma unroll
  for (int nn = 0; nn < 4; ++nn) {
    A4[nn] = -__expf(alog[i * 16 + ns * 4 + nn]);
    wr4[nn] = dtw[i * 16 + ns * 4 + nn];
  }
  float dtbi = dtb[i], Di = Dp[i];
  float st0 = 0.f, st1 = 0.f, st2 = 0.f, st3 = 0.f;
  size_t rowL = (size_t)b * 512;

#pragma unroll 1
  for (int c = 0; c < 512; c += CL) {
    __syncthreads();
    {
      const float* src = ssm + (rowL + c) * 48;
      for (int t = tid; t < CL * 48; t += 256) sbuf[t] = src[t];
    }
    for (int t = tid; t < CL * 64; t += 256) {
      int lc = t >> 6, ci = t & 63;
      ubuf[lc][ci] = u2[(rowL + c + lc) * 512 + i0 + ci];
      gbuf[lc][ci] = proj[(rowL + c + lc) * 1024 + 512 + i0 + ci];
    }
    __syncthreads();
    for (int ll = 0; ll < CL; ++ll) {
      const float* row = &sbuf[ll * 48];
      float4 dtr = *(const float4*)(row + ns * 4);
      float pdt = dtr.x * wr4[0] + dtr.y * wr4[1] + dtr.z * wr4[2] + dtr.w * wr4[3];
      pdt += __shfl_xor(pdt, 1);
      pdt += __shfl_xor(pdt, 2);
      pdt += dtbi;
      float dtv = (pdt > 20.0f) ? pdt : __logf(1.0f + __expf(pdt));
      float u = ubuf[ll][il];
      float dtu = dtv * u;
      float4 Bv = *(const float4*)(row + 16 + ns * 4);
      float4 Cv = *(const float4*)(row + 32 + ns * 4);
      st0 = st0 * __expf(dtv * A4[0]) + dtu * Bv.x;
      st1 = st1 * __expf(dtv * A4[1]) + dtu * Bv.y;
      st2 = st2 * __expf(dtv * A4[2]) + dtu * Bv.z;
      st3 = st3 * __expf(dtv * A4[3]) + dtu * Bv.w;
      float yp = st0 * Cv.x + st1 * Cv.y + st2 * Cv.z + st3 * Cv.w;
      yp += __shfl_xor(yp, 1);
      yp += __shfl_xor(yp, 2);
      if (ns == 0) {
        float gt = gbuf[ll][il];
        ubuf[ll][il] = (yp + u * Di) * siluf(gt);
      }
    }
    __syncthreads();
    for (int t = tid; t < CL * 64; t += 256) {
      int lc = t >> 6, ci = t & 63;
      u2[(rowL + c + lc) * 512 + i0 + ci] = ubuf[lc][ci];
    }
  }
}

// ---- mean/max pool over L after final rmsnorm; writes emb into d_out+32
__global__ __launch_bounds__(64) void pool_kernel(const float* __restrict__ hn, float* __restrict__ outp)
{
  int c = blockIdx.x * 64 + threadIdx.x;
  int b = blockIdx.y;
  float s = 0.0f, mx = -3.4e38f;
  for (int l = 0; l < 512; ++l) {
    float v = hn[((size_t)b * 512 + l) * 256 + c];
    s += v;
    mx = fmaxf(mx, v);
  }
  outp[32 + b * 512 + c] = s * (1.0f / 512.0f);
  outp[32 + b * 512 + 256 + c] = mx;
}

// ---- KAN-2 head: (16, 512) -> (16, 2). One block per b.
__global__ __launch_bounds__(256) void kan2_kernel(
    const float* __restrict__ outp, const float* __restrict__ bw2, const float* __restrict__ sw2,
    const float* __restrict__ ss2, float* __restrict__ logits)
{
  __shared__ float r0[256], r1[256];
  int b = blockIdx.x, tid = threadIdx.x;
  float a0 = 0.0f, a1 = 0.0f;
#pragma unroll
  for (int dd = 0; dd < 2; ++dd) {
    int d = tid + dd * 256;
    float e = outp[32 + b * 512 + d];
    float bb[8];
    bspline8(e, bb);
    float sl = siluf(e);
    {
      float sc = ss2[d];
      const float* sp = &sw2[(size_t)d * 8];
      float t = sl * bw2[d];
      t += (bb[0] * sp[0] + bb[1] * sp[1] + bb[2] * sp[2] + bb[3] * sp[3]
          + bb[4] * sp[4] + bb[5] * sp[5] + bb[6] * sp[6] + bb[7] * sp[7]) * sc;
      a0 += t;
    }
    {
      float sc = ss2[512 + d];
      const float* sp = &sw2[(size_t)(512 + d) * 8];
      float t = sl * bw2[512 + d];
      t += (bb[0] * sp[0] + bb[1] * sp[1] + bb[2] * sp[2] + bb[3] * sp[3]
          + bb[4] * sp[4] + bb[5] * sp[5] + bb[6] * sp[6] + bb[7] * sp[7]) * sc;
      a1 += t;
    }
  }
  r0[tid] = a0; r1[tid] = a1;
  __syncthreads();
  for (int s = 128; s > 0; s >>= 1) {
    if (tid < s) { r0[tid] += r0[tid + s]; r1[tid] += r1[tid + s]; }
    __syncthreads();
  }
  if (tid == 0) { logits[b * 2 + 0] = r0[0]; logits[b * 2 + 1] = r1[0]; }
}

extern "C" void kernel_launch(void* const* d_in, const int* in_sizes, int n_in,
                              void* d_out, int out_size, void* d_ws, size_t ws_size,
                              hipStream_t stream)
{
  const float* x     = (const float*)d_in[0];
  const float* bw1   = (const float*)d_in[1];
  const float* sw1   = (const float*)d_in[2];
  const float* ss1   = (const float*)d_in[3];
  const float* lng   = (const float*)d_in[4];
  const float* lnb   = (const float*)d_in[5];
  const float* normw = (const float*)d_in[6];
  const float* ipw   = (const float*)d_in[7];
  const float* cw    = (const float*)d_in[8];
  const float* cb    = (const float*)d_in[9];
  const float* xpw   = (const float*)d_in[10];
  const float* dtw   = (const float*)d_in[11];
  const float* dtb   = (const float*)d_in[12];
  const float* alog  = (const float*)d_in[13];
  const float* Dp    = (const float*)d_in[14];
  const float* opw   = (const float*)d_in[15];
  const float* nfw   = (const float*)d_in[16];
  const float* bw2   = (const float*)d_in[17];
  const float* sw2   = (const float*)d_in[18];
  const float* ss2   = (const float*)d_in[19];
  float* out = (float*)d_out;

  float* ws   = (float*)d_ws;
  float* W1b  = ws;                       // 196608
  float* W1s  = W1b + 196608;             // 1572864
  float* h    = W1s + 1572864;            // 2097152
  float* xn   = h + 2097152;              // 2097152
  float* proj = xn + 2097152;             // 8388608
  float* u2   = proj + 8388608;           // 4194304
  float* ssmb = u2 + 4194304;             // 393216  -> total ~75.8 MB

  prep_w1_kernel<<<768, 256, 0, stream>>>(bw1, sw1, ss1, W1b, W1s);
  kan1_ln_kernel<<<256, 512, 0, stream>>>(x, W1b, W1s, lng, lnb, h);

  for (int l = 0; l < 2; ++l) {
    rmsnorm_kernel<<<8192, 256, 0, stream>>>(h, normw + l * 256, xn);
    // in_proj: (8192,256)@(1024,256)^T -> (8192,1024)
    gemm128<2, 0><<<dim3(64, 8), 256, 0, stream>>>(xn, ipw + (size_t)l * 262144, proj, 1024, 256);
    conv_silu_kernel<<<16384, 256, 0, stream>>>(proj, cw + l * 2048, cb + l * 512, u2);
    // x_proj: (8192,512)@(48,512)^T -> (8192,48)
    gemm_nt<0><<<dim3(128, 1), 256, 0, stream>>>(u2, xpw + (size_t)l * 24576, ssmb, 8192, 48, 512);
    scan_kernel<<<dim3(8, 16), 256, 0, stream>>>(ssmb, u2, proj,
                                                 dtw + l * 8192, dtb + l * 512,
                                                 alog + l * 8192, Dp + l * 512);
    // out_proj (+residual): (8192,512)@(256,512)^T += h
    gemm128<1, 1><<<dim3(64, 4), 256, 0, stream>>>(u2, opw + (size_t)l * 131072, h, 256, 512);
  }

  rmsnorm_kernel<<<8192, 256, 0, stream>>>(h, nfw, xn);
  pool_kernel<<<dim3(4, 16), 64, 0, stream>>>(xn, out);
  kan2_kernel<<<16, 256, 0, stream>>>(out, bw2, sw2, ss2, out);
}